// Round 2
// baseline (332.657 us; speedup 1.0000x reference)
//
#include <hip/hip_runtime.h>
#include <math.h>

#define BATCH 4
#define NPTS  65536
#define KNBR  16
#define DF    32
#define NPOOL 16384   // NPTS/4

// ---------------- Kernel 1: relative position encoding --------------------
// One thread per (b,n,k) entry; stage 10-float rows in LDS, write coalesced.
__global__ __launch_bounds__(256) void relpos_kernel(
    const float* __restrict__ xyz, const int* __restrict__ nidx,
    float* __restrict__ out)
{
    __shared__ float s[2560];                 // 256 entries x 10 floats
    const int tid = threadIdx.x;
    const int e = blockIdx.x * 256 + tid;     // b*2^20 + n*16 + k
    const int b = e >> 20;
    const int n = (e >> 4) & (NPTS - 1);
    const int j = nidx[e];
    const float* c = xyz + (size_t)(b * NPTS + n) * 3;
    const float* g = xyz + (size_t)(b * NPTS + j) * 3;
    const float cx = c[0], cy = c[1], cz = c[2];
    const float nx = g[0], ny = g[1], nz = g[2];
    const float rx = cx - nx, ry = cy - ny, rz = cz - nz;
    const float dist = sqrtf(rx * rx + ry * ry + rz * rz);
    float* st = s + tid * 10;
    st[0] = dist; st[1] = rx; st[2] = ry; st[3] = rz;
    st[4] = cx;   st[5] = cy; st[6] = cz;
    st[7] = nx;   st[8] = ny; st[9] = nz;
    __syncthreads();
    float4* o4 = (float4*)(out + (size_t)blockIdx.x * 2560);
    const float4* s4 = (const float4*)s;
    o4[tid]       = s4[tid];
    o4[tid + 256] = s4[tid + 256];
    if (tid < 128) o4[tid + 512] = s4[tid + 512];
}

// ---------------- Transpose [b][d][nn] -> [b][nn][d] ----------------------
__global__ __launch_bounds__(256) void transpose_kernel(
    const float* __restrict__ in, float* __restrict__ outp, int nn)
{
    __shared__ float tile[32][33];
    const int tpb = nn >> 5;                  // 32-wide tiles per batch
    const int b  = blockIdx.x / tpb;
    const int n0 = (blockIdx.x % tpb) << 5;
    const int t  = threadIdx.x;
    const int nl = t & 31;
    const int dl = t >> 5;                    // 0..7
    #pragma unroll
    for (int it = 0; it < 4; ++it) {
        const int d = dl + it * 8;
        tile[d][nl] = in[(size_t)(b * DF + d) * nn + n0 + nl];
    }
    __syncthreads();
    #pragma unroll
    for (int it = 0; it < 4; ++it) {
        const int n = dl + it * 8;
        outp[((size_t)b * nn + n0 + n) * DF + nl] = tile[nl][n];
    }
}

// ---------------- Kernel 2: max-pool gather (transposed feat) -------------
// Block = (b, 64 np, all 32 d). d-fastest lanes -> 128B coalesced gathers.
__global__ __launch_bounds__(256) void pool_kernel_t(
    const float* __restrict__ ft, const int* __restrict__ pidx,
    float* __restrict__ out)
{
    __shared__ int   s_idx[64 * KNBR];
    __shared__ float s_out[64 * 33];
    const int t   = threadIdx.x;
    const int bpb = NPOOL / 64;
    const int b   = blockIdx.x / bpb;
    const int np0 = (blockIdx.x % bpb) * 64;
    const int4* src4 = (const int4*)(pidx + (size_t)(b * NPOOL + np0) * KNBR);
    ((int4*)s_idx)[t] = src4[t];              // 1024 ints == 256 int4
    __syncthreads();
    const int d = t & 31;
    const int g = t >> 5;
    const float* fb = ft + (size_t)b * NPTS * DF;
    #pragma unroll
    for (int r = 0; r < 8; ++r) {
        const int ul = g * 8 + r;
        float m = -INFINITY;
        #pragma unroll
        for (int k = 0; k < KNBR; ++k) {
            const int idx = s_idx[ul * KNBR + k];
            m = fmaxf(m, fb[(size_t)idx * DF + d]);
        }
        s_out[ul * 33 + d] = m;
    }
    __syncthreads();
    #pragma unroll
    for (int w = 0; w < 8; ++w) {
        const int flat = w * 256 + t;
        const int u  = flat & 63;
        const int dd = flat >> 6;
        out[(size_t)(b * DF + dd) * NPOOL + np0 + u] = s_out[u * 33 + dd];
    }
}

// ---------------- Kernel 3: nearest interpolation (transposed feat) -------
__global__ __launch_bounds__(256) void interp_kernel_t(
    const float* __restrict__ ft, const int* __restrict__ iidx,
    float* __restrict__ out)
{
    __shared__ int   s_idx[64];
    __shared__ float s_out[64 * 33];
    const int t   = threadIdx.x;
    const int bpb = NPTS / 64;
    const int b   = blockIdx.x / bpb;
    const int u0  = (blockIdx.x % bpb) * 64;
    if (t < 64) s_idx[t] = iidx[b * NPTS + u0 + t];
    __syncthreads();
    const int d = t & 31;
    const int g = t >> 5;
    const float* fb = ft + (size_t)b * NPOOL * DF;
    #pragma unroll
    for (int r = 0; r < 8; ++r) {
        const int ul = g * 8 + r;
        s_out[ul * 33 + d] = fb[(size_t)s_idx[ul] * DF + d];
    }
    __syncthreads();
    #pragma unroll
    for (int w = 0; w < 8; ++w) {
        const int flat = w * 256 + t;
        const int u  = flat & 63;
        const int dd = flat >> 6;
        out[(size_t)(b * DF + dd) * NPTS + u0 + u] = s_out[u * 33 + dd];
    }
}

// ---------------- Fallback (no workspace) naive gathers -------------------
__global__ __launch_bounds__(256) void pool_kernel_naive(
    const float* __restrict__ feat, const int* __restrict__ pidx,
    float* __restrict__ out)
{
    const int i  = blockIdx.x * 256 + threadIdx.x;   // (b,d,np), np fastest
    const int np = i & (NPOOL - 1);
    const int bd = i >> 14;
    const int b  = bd >> 5;
    const int4* ip = (const int4*)(pidx + (size_t)(b * NPOOL + np) * KNBR);
    const float* f = feat + (size_t)bd * NPTS;
    float m = -INFINITY;
    #pragma unroll
    for (int q = 0; q < 4; ++q) {
        const int4 v = ip[q];
        m = fmaxf(m, f[v.x]); m = fmaxf(m, f[v.y]);
        m = fmaxf(m, f[v.z]); m = fmaxf(m, f[v.w]);
    }
    out[i] = m;
}

__global__ __launch_bounds__(256) void interp_kernel_naive(
    const float* __restrict__ feat, const int* __restrict__ iidx,
    float* __restrict__ out)
{
    const int i  = blockIdx.x * 256 + threadIdx.x;   // (b,d,u), u fastest
    const int u  = i & (NPTS - 1);
    const int bd = i >> 16;
    const int b  = bd >> 5;
    out[i] = feat[(size_t)bd * NPOOL + iidx[b * NPTS + u]];
}

extern "C" void kernel_launch(void* const* d_in, const int* in_sizes, int n_in,
                              void* d_out, int out_size, void* d_ws, size_t ws_size,
                              hipStream_t stream) {
    const float* xyz         = (const float*)d_in[0];
    const int*   neigh_idx   = (const int*)d_in[1];
    const float* feat_pool   = (const float*)d_in[2];
    const int*   pool_idx    = (const int*)d_in[3];
    const float* feat_interp = (const float*)d_in[4];
    const int*   interp_idx  = (const int*)d_in[5];

    float* out    = (float*)d_out;
    float* rel    = out;                                        // [4,65536,16,10]
    float* pooled = rel + (size_t)BATCH * NPTS * KNBR * 10;     // [4,32,16384]
    float* interp = pooled + (size_t)BATCH * DF * NPOOL;        // [4,32,65536]

    relpos_kernel<<<(BATCH * NPTS * KNBR) / 256, 256, 0, stream>>>(xyz, neigh_idx, rel);

    const size_t need = ((size_t)BATCH * DF * NPTS + (size_t)BATCH * DF * NPOOL) * sizeof(float);
    if (ws_size >= need) {
        float* ftp = (float*)d_ws;                              // [4,65536,32]
        float* fti = ftp + (size_t)BATCH * DF * NPTS;           // [4,16384,32]
        transpose_kernel<<<BATCH * (NPTS / 32), 256, 0, stream>>>(feat_pool, ftp, NPTS);
        transpose_kernel<<<BATCH * (NPOOL / 32), 256, 0, stream>>>(feat_interp, fti, NPOOL);
        pool_kernel_t<<<BATCH * (NPOOL / 64), 256, 0, stream>>>(ftp, pool_idx, pooled);
        interp_kernel_t<<<BATCH * (NPTS / 64), 256, 0, stream>>>(fti, interp_idx, interp);
    } else {
        pool_kernel_naive<<<(BATCH * DF * NPOOL) / 256, 256, 0, stream>>>(feat_pool, pool_idx, pooled);
        interp_kernel_naive<<<(BATCH * DF * NPTS) / 256, 256, 0, stream>>>(feat_interp, interp_idx, interp);
    }
}

// Round 4
// 321.925 us; speedup vs baseline: 1.0333x; 1.0333x over previous
//
#include <hip/hip_runtime.h>
#include <math.h>

#define BATCH 4
#define NPTS  65536
#define KNBR  16
#define DF    32
#define NPOOL 16384   // NPTS/4

// ws layout: ftp [B][NPTS][32] | fti [B][NPOOL][32] | xyz4 [B][NPTS][4]
#define FTP_ELEMS   ((size_t)BATCH * NPTS * DF)
#define FTI_ELEMS   ((size_t)BATCH * NPOOL * DF)
#define XYZ4_ELEMS  ((size_t)BATCH * NPTS * 4)

// ============ Kernel 1: fused prep (2 transposes + xyz pad) ==============
#define T1_BLKS (BATCH * (NPTS / 32))    // 8192
#define T2_BLKS (BATCH * (NPOOL / 32))   // 2048
#define T3_BLKS ((BATCH * NPTS) / 256)   // 1024
__global__ __launch_bounds__(256) void prep_kernel(
    const float* __restrict__ feat_pool, const float* __restrict__ feat_interp,
    const float* __restrict__ xyz,
    float* __restrict__ ftp, float* __restrict__ fti, float* __restrict__ xyz4)
{
    __shared__ float tile[32][33];
    const int bid = blockIdx.x;
    const int t = threadIdx.x;
    if (bid < T1_BLKS + T2_BLKS) {
        const float* in; float* outp; int nn, tb;
        if (bid < T1_BLKS) { in = feat_pool;  outp = ftp; nn = NPTS;  tb = bid; }
        else               { in = feat_interp; outp = fti; nn = NPOOL; tb = bid - T1_BLKS; }
        const int tpb = nn >> 5;
        const int b  = tb / tpb;
        const int n0 = (tb % tpb) << 5;
        const int nl = t & 31;
        const int dl = t >> 5;
        #pragma unroll
        for (int it = 0; it < 4; ++it) {
            const int d = dl + it * 8;
            tile[d][nl] = in[(size_t)(b * DF + d) * nn + n0 + nl];
        }
        __syncthreads();
        #pragma unroll
        for (int it = 0; it < 4; ++it) {
            const int n = dl + it * 8;
            outp[((size_t)b * nn + n0 + n) * DF + nl] = tile[nl][n];
        }
    } else {
        const int p = (bid - T1_BLKS - T2_BLKS) * 256 + t;   // point id over B*NPTS
        const float x = xyz[(size_t)p * 3 + 0];
        const float y = xyz[(size_t)p * 3 + 1];
        const float z = xyz[(size_t)p * 3 + 2];
        ((float4*)xyz4)[p] = make_float4(x, y, z, 0.f);
    }
}

// ============ Kernel 2: fused main (relpos + pool + interp) ==============
// block-type interleave: per group of 21 blocks -> 16 relpos, 1 pool, 4 interp
#define R_BLKS 16384   // (B*N*K)/256
#define P_BLKS 1024    // B * NPOOL/64
#define I_BLKS 4096    // B * NPTS/64
#define MAIN_BLKS (R_BLKS + P_BLKS + I_BLKS)   // 21504 = 21*1024

__global__ __launch_bounds__(256) void fused_main(
    const float* __restrict__ xyz4, const int* __restrict__ nidx,
    const float* __restrict__ ftp,  const int* __restrict__ pidx,
    const float* __restrict__ fti,  const int* __restrict__ iidx,
    float* __restrict__ rel, float* __restrict__ pooled, float* __restrict__ interp)
{
    __shared__ char smem[12800];
    const int g = blockIdx.x / 21;
    const int m = blockIdx.x % 21;
    const int t = threadIdx.x;

    if (m < 16) {
        // ---------------- relpos: block handles 256 (b,n,k) entries -------
        float* s = (float*)smem;                       // 2560 floats
        const int rblk = g * 16 + m;
        const int e = rblk * 256 + t;                  // b*2^20 + n*16 + k
        const int b = e >> 20;
        const int n = (e >> 4) & (NPTS - 1);
        const int j = nidx[e];
        const float4 c = ((const float4*)xyz4)[b * NPTS + n];
        const float4 q = ((const float4*)xyz4)[b * NPTS + j];
        const float rx = c.x - q.x, ry = c.y - q.y, rz = c.z - q.z;
        const float dist = sqrtf(rx * rx + ry * ry + rz * rz);
        float* st = s + t * 10;
        st[0] = dist; st[1] = rx;  st[2] = ry;  st[3] = rz;
        st[4] = c.x;  st[5] = c.y; st[6] = c.z;
        st[7] = q.x;  st[8] = q.y; st[9] = q.z;
        __syncthreads();
        float4* o4 = (float4*)(rel + (size_t)rblk * 2560);
        const float4* s4 = (const float4*)s;
        o4[t]       = s4[t];
        o4[t + 256] = s4[t + 256];
        if (t < 128) o4[t + 512] = s4[t + 512];
    } else if (m == 16) {
        // ---------------- pool: block handles (b, 64 np rows) -------------
        int*   s_idx = (int*)smem;                     // 1024 ints
        float* s_out = (float*)(smem + 4096);          // 64*33 floats
        const int bpb = NPOOL / 64;                    // 256
        const int b   = g / bpb;
        const int np0 = (g % bpb) * 64;
        ((int4*)s_idx)[t] = ((const int4*)(pidx + (size_t)(b * NPOOL + np0) * KNBR))[t];
        __syncthreads();
        const float4* fb4 = (const float4*)(ftp + (size_t)b * NPTS * DF);
        const int l8 = t & 7;                          // 8 lanes x float4 = 32 d
        #pragma unroll
        for (int it = 0; it < 2; ++it) {
            const int u = (t >> 3) + it * 32;
            float4 acc = make_float4(-INFINITY, -INFINITY, -INFINITY, -INFINITY);
            #pragma unroll
            for (int k = 0; k < KNBR; ++k) {
                const int idx = s_idx[u * KNBR + k];
                const float4 v = fb4[(size_t)idx * 8 + l8];
                acc.x = fmaxf(acc.x, v.x); acc.y = fmaxf(acc.y, v.y);
                acc.z = fmaxf(acc.z, v.z); acc.w = fmaxf(acc.w, v.w);
            }
            float* so = s_out + u * 33 + l8 * 4;
            so[0] = acc.x; so[1] = acc.y; so[2] = acc.z; so[3] = acc.w;
        }
        __syncthreads();
        #pragma unroll
        for (int w = 0; w < 8; ++w) {
            const int flat = w * 256 + t;
            const int u  = flat & 63;
            const int dd = flat >> 6;
            pooled[(size_t)(b * DF + dd) * NPOOL + np0 + u] = s_out[u * 33 + dd];
        }
    } else {
        // ---------------- interp: block handles (b, 64 u rows) ------------
        int*   s_idx = (int*)smem;                     // 64 ints
        float* s_out = (float*)(smem + 256);           // 64*33 floats
        const int i   = g * 4 + (m - 17);
        const int bpb = NPTS / 64;                     // 1024
        const int b   = i / bpb;
        const int u0  = (i % bpb) * 64;
        if (t < 64) s_idx[t] = iidx[b * NPTS + u0 + t];
        __syncthreads();
        const float4* fb4 = (const float4*)(fti + (size_t)b * NPOOL * DF);
        const int l8 = t & 7;
        #pragma unroll
        for (int it = 0; it < 2; ++it) {
            const int u = (t >> 3) + it * 32;
            const int idx = s_idx[u];
            const float4 v = fb4[(size_t)idx * 8 + l8];
            float* so = s_out + u * 33 + l8 * 4;
            so[0] = v.x; so[1] = v.y; so[2] = v.z; so[3] = v.w;
        }
        __syncthreads();
        #pragma unroll
        for (int w = 0; w < 8; ++w) {
            const int flat = w * 256 + t;
            const int u  = flat & 63;
            const int dd = flat >> 6;
            interp[(size_t)(b * DF + dd) * NPTS + u0 + u] = s_out[u * 33 + dd];
        }
    }
}

// ================== Fallback path (ws too small) =========================
__global__ __launch_bounds__(256) void relpos_kernel(
    const float* __restrict__ xyz, const int* __restrict__ nidx,
    float* __restrict__ out)
{
    __shared__ float s[2560];
    const int tid = threadIdx.x;
    const int e = blockIdx.x * 256 + tid;
    const int b = e >> 20;
    const int n = (e >> 4) & (NPTS - 1);
    const int j = nidx[e];
    const float* c = xyz + (size_t)(b * NPTS + n) * 3;
    const float* g = xyz + (size_t)(b * NPTS + j) * 3;
    const float cx = c[0], cy = c[1], cz = c[2];
    const float nx = g[0], ny = g[1], nz = g[2];
    const float rx = cx - nx, ry = cy - ny, rz = cz - nz;
    const float dist = sqrtf(rx * rx + ry * ry + rz * rz);
    float* st = s + tid * 10;
    st[0] = dist; st[1] = rx; st[2] = ry; st[3] = rz;
    st[4] = cx;   st[5] = cy; st[6] = cz;
    st[7] = nx;   st[8] = ny; st[9] = nz;
    __syncthreads();
    float4* o4 = (float4*)(out + (size_t)blockIdx.x * 2560);
    const float4* s4 = (const float4*)s;
    o4[tid]       = s4[tid];
    o4[tid + 256] = s4[tid + 256];
    if (tid < 128) o4[tid + 512] = s4[tid + 512];
}

__global__ __launch_bounds__(256) void pool_kernel_naive(
    const float* __restrict__ feat, const int* __restrict__ pidx,
    float* __restrict__ out)
{
    const int i  = blockIdx.x * 256 + threadIdx.x;
    const int np = i & (NPOOL - 1);
    const int bd = i >> 14;
    const int b  = bd >> 5;
    const int4* ip = (const int4*)(pidx + (size_t)(b * NPOOL + np) * KNBR);
    const float* f = feat + (size_t)bd * NPTS;
    float m = -INFINITY;
    #pragma unroll
    for (int q = 0; q < 4; ++q) {
        const int4 v = ip[q];
        m = fmaxf(m, f[v.x]); m = fmaxf(m, f[v.y]);
        m = fmaxf(m, f[v.z]); m = fmaxf(m, f[v.w]);
    }
    out[i] = m;
}

__global__ __launch_bounds__(256) void interp_kernel_naive(
    const float* __restrict__ feat, const int* __restrict__ iidx,
    float* __restrict__ out)
{
    const int i  = blockIdx.x * 256 + threadIdx.x;
    const int u  = i & (NPTS - 1);
    const int bd = i >> 16;
    const int b  = bd >> 5;
    out[i] = feat[(size_t)bd * NPOOL + iidx[b * NPTS + u]];
}

extern "C" void kernel_launch(void* const* d_in, const int* in_sizes, int n_in,
                              void* d_out, int out_size, void* d_ws, size_t ws_size,
                              hipStream_t stream) {
    const float* xyz         = (const float*)d_in[0];
    const int*   neigh_idx   = (const int*)d_in[1];
    const float* feat_pool   = (const float*)d_in[2];
    const int*   pool_idx    = (const int*)d_in[3];
    const float* feat_interp = (const float*)d_in[4];
    const int*   interp_idx  = (const int*)d_in[5];

    float* out    = (float*)d_out;
    float* rel    = out;                                        // [4,65536,16,10]
    float* pooled = rel + (size_t)BATCH * NPTS * KNBR * 10;     // [4,32,16384]
    float* interp = pooled + (size_t)BATCH * DF * NPOOL;        // [4,32,65536]

    const size_t need = (FTP_ELEMS + FTI_ELEMS + XYZ4_ELEMS) * sizeof(float);
    if (ws_size >= need) {
        float* ftp  = (float*)d_ws;
        float* fti  = ftp + FTP_ELEMS;
        float* xyz4 = fti + FTI_ELEMS;
        prep_kernel<<<T1_BLKS + T2_BLKS + T3_BLKS, 256, 0, stream>>>(
            feat_pool, feat_interp, xyz, ftp, fti, xyz4);
        fused_main<<<MAIN_BLKS, 256, 0, stream>>>(
            xyz4, neigh_idx, ftp, pool_idx, fti, interp_idx, rel, pooled, interp);
    } else {
        relpos_kernel<<<(BATCH * NPTS * KNBR) / 256, 256, 0, stream>>>(xyz, neigh_idx, rel);
        pool_kernel_naive<<<(BATCH * DF * NPOOL) / 256, 256, 0, stream>>>(feat_pool, pool_idx, pooled);
        interp_kernel_naive<<<(BATCH * DF * NPTS) / 256, 256, 0, stream>>>(feat_interp, interp_idx, interp);
    }
}

// Round 7
// 312.170 us; speedup vs baseline: 1.0656x; 1.0312x over previous
//
#include <hip/hip_runtime.h>
#include <math.h>

#define BATCH 4
#define NPTS  65536
#define KNBR  16
#define DF    32
#define NPOOL 16384   // NPTS/4

typedef float f32x4 __attribute__((ext_vector_type(4)));

// ws layout: ftp [B][NPTS][32] | fti [B][NPOOL][32] | xyz4 [B][NPTS][4]
#define FTP_ELEMS   ((size_t)BATCH * NPTS * DF)
#define FTI_ELEMS   ((size_t)BATCH * NPOOL * DF)
#define XYZ4_ELEMS  ((size_t)BATCH * NPTS * 4)

// ============ Kernel 1: fused prep (2 transposes + xyz pad) ==============
#define T1_BLKS (BATCH * (NPTS / 32))    // 8192
#define T2_BLKS (BATCH * (NPOOL / 32))   // 2048
#define T3_BLKS ((BATCH * NPTS) / 256)   // 1024
__global__ __launch_bounds__(256) void prep_kernel(
    const float* __restrict__ feat_pool, const float* __restrict__ feat_interp,
    const float* __restrict__ xyz,
    float* __restrict__ ftp, float* __restrict__ fti, float* __restrict__ xyz4)
{
    __shared__ float tile[32][33];
    const int bid = blockIdx.x;
    const int t = threadIdx.x;
    if (bid < T1_BLKS + T2_BLKS) {
        const float* in; float* outp; int nn, tb;
        if (bid < T1_BLKS) { in = feat_pool;  outp = ftp; nn = NPTS;  tb = bid; }
        else               { in = feat_interp; outp = fti; nn = NPOOL; tb = bid - T1_BLKS; }
        const int tpb = nn >> 5;
        const int b  = tb / tpb;
        const int n0 = (tb % tpb) << 5;
        const int nl = t & 31;
        const int dl = t >> 5;
        #pragma unroll
        for (int it = 0; it < 4; ++it) {
            const int d = dl + it * 8;
            // one-pass read: NT load (keep L2/L3 clean for the gather tables)
            tile[d][nl] = __builtin_nontemporal_load(&in[(size_t)(b * DF + d) * nn + n0 + nl]);
        }
        __syncthreads();
        #pragma unroll
        for (int it = 0; it < 4; ++it) {
            const int n = dl + it * 8;
            // ftp/fti are re-read by fused_main -> normal (cacheable) store
            outp[((size_t)b * nn + n0 + n) * DF + nl] = tile[nl][n];
        }
    } else {
        const int p = (bid - T1_BLKS - T2_BLKS) * 256 + t;   // point id over B*NPTS
        const float x = __builtin_nontemporal_load(&xyz[(size_t)p * 3 + 0]);
        const float y = __builtin_nontemporal_load(&xyz[(size_t)p * 3 + 1]);
        const float z = __builtin_nontemporal_load(&xyz[(size_t)p * 3 + 2]);
        f32x4 v = { x, y, z, 0.f };
        ((f32x4*)xyz4)[p] = v;       // re-read by fused_main -> cacheable
    }
}

// ============ Kernel 2: fused main (relpos + pool + interp) ==============
// block-type interleave: per group of 21 blocks -> 16 relpos, 1 pool, 4 interp
#define R_BLKS 16384   // (B*N*K)/256
#define P_BLKS 1024    // B * NPOOL/64
#define I_BLKS 4096    // B * NPTS/64
#define MAIN_BLKS (R_BLKS + P_BLKS + I_BLKS)   // 21504 = 21*1024

__global__ __launch_bounds__(256) void fused_main(
    const float* __restrict__ xyz4, const int* __restrict__ nidx,
    const float* __restrict__ ftp,  const int* __restrict__ pidx,
    const float* __restrict__ fti,  const int* __restrict__ iidx,
    float* __restrict__ rel, float* __restrict__ pooled, float* __restrict__ interp)
{
    __shared__ char smem[12800];
    const int g = blockIdx.x / 21;
    const int m = blockIdx.x % 21;
    const int t = threadIdx.x;

    if (m < 16) {
        // ---------------- relpos: block handles 256 (b,n,k) entries -------
        float* s = (float*)smem;                       // 2560 floats
        const int rblk = g * 16 + m;
        const int e = rblk * 256 + t;                  // b*2^20 + n*16 + k
        const int b = e >> 20;
        const int n = (e >> 4) & (NPTS - 1);
        const int j = __builtin_nontemporal_load(&nidx[e]);  // one-pass stream
        const float4 c = ((const float4*)xyz4)[b * NPTS + n];
        const float4 q = ((const float4*)xyz4)[b * NPTS + j];
        const float rx = c.x - q.x, ry = c.y - q.y, rz = c.z - q.z;
        const float dist = sqrtf(rx * rx + ry * ry + rz * rz);
        float* st = s + t * 10;
        st[0] = dist; st[1] = rx;  st[2] = ry;  st[3] = rz;
        st[4] = c.x;  st[5] = c.y; st[6] = c.z;
        st[7] = q.x;  st[8] = q.y; st[9] = q.z;
        __syncthreads();
        f32x4* o4 = (f32x4*)(rel + (size_t)rblk * 2560);
        const f32x4* s4 = (const f32x4*)smem;
        __builtin_nontemporal_store(s4[t],       &o4[t]);        // 210MB stream:
        __builtin_nontemporal_store(s4[t + 256], &o4[t + 256]);  // bypass L2/L3
        if (t < 128) __builtin_nontemporal_store(s4[t + 512], &o4[t + 512]);
    } else if (m == 16) {
        // ---------------- pool: block handles (b, 64 np rows) -------------
        int*   s_idx = (int*)smem;                     // 1024 ints
        float* s_out = (float*)(smem + 4096);          // 64*33 floats
        const int bpb = NPOOL / 64;                    // 256
        const int b   = g / bpb;
        const int np0 = (g % bpb) * 64;
        ((int4*)s_idx)[t] = ((const int4*)(pidx + (size_t)(b * NPOOL + np0) * KNBR))[t];
        __syncthreads();
        const float4* fb4 = (const float4*)(ftp + (size_t)b * NPTS * DF);
        const int l8 = t & 7;                          // 8 lanes x float4 = 32 d
        #pragma unroll
        for (int it = 0; it < 2; ++it) {
            const int u = (t >> 3) + it * 32;
            float4 acc = make_float4(-INFINITY, -INFINITY, -INFINITY, -INFINITY);
            #pragma unroll
            for (int k = 0; k < KNBR; ++k) {
                const int idx = s_idx[u * KNBR + k];
                const float4 v = fb4[(size_t)idx * 8 + l8];
                acc.x = fmaxf(acc.x, v.x); acc.y = fmaxf(acc.y, v.y);
                acc.z = fmaxf(acc.z, v.z); acc.w = fmaxf(acc.w, v.w);
            }
            float* so = s_out + u * 33 + l8 * 4;
            so[0] = acc.x; so[1] = acc.y; so[2] = acc.z; so[3] = acc.w;
        }
        __syncthreads();
        #pragma unroll
        for (int w = 0; w < 8; ++w) {
            const int flat = w * 256 + t;
            const int u  = flat & 63;
            const int dd = flat >> 6;
            __builtin_nontemporal_store(s_out[u * 33 + dd],
                &pooled[(size_t)(b * DF + dd) * NPOOL + np0 + u]);
        }
    } else {
        // ---------------- interp: block handles (b, 64 u rows) ------------
        int*   s_idx = (int*)smem;                     // 64 ints
        float* s_out = (float*)(smem + 256);           // 64*33 floats
        const int i   = g * 4 + (m - 17);
        const int bpb = NPTS / 64;                     // 1024
        const int b   = i / bpb;
        const int u0  = (i % bpb) * 64;
        if (t < 64) s_idx[t] = iidx[b * NPTS + u0 + t];
        __syncthreads();
        const float4* fb4 = (const float4*)(fti + (size_t)b * NPOOL * DF);
        const int l8 = t & 7;
        #pragma unroll
        for (int it = 0; it < 2; ++it) {
            const int u = (t >> 3) + it * 32;
            const int idx = s_idx[u];
            const float4 v = fb4[(size_t)idx * 8 + l8];
            float* so = s_out + u * 33 + l8 * 4;
            so[0] = v.x; so[1] = v.y; so[2] = v.z; so[3] = v.w;
        }
        __syncthreads();
        #pragma unroll
        for (int w = 0; w < 8; ++w) {
            const int flat = w * 256 + t;
            const int u  = flat & 63;
            const int dd = flat >> 6;
            __builtin_nontemporal_store(s_out[u * 33 + dd],
                &interp[(size_t)(b * DF + dd) * NPTS + u0 + u]);
        }
    }
}

// ================== Fallback path (ws too small) =========================
__global__ __launch_bounds__(256) void relpos_kernel(
    const float* __restrict__ xyz, const int* __restrict__ nidx,
    float* __restrict__ out)
{
    __shared__ float s[2560];
    const int tid = threadIdx.x;
    const int e = blockIdx.x * 256 + tid;
    const int b = e >> 20;
    const int n = (e >> 4) & (NPTS - 1);
    const int j = nidx[e];
    const float* c = xyz + (size_t)(b * NPTS + n) * 3;
    const float* g = xyz + (size_t)(b * NPTS + j) * 3;
    const float cx = c[0], cy = c[1], cz = c[2];
    const float nx = g[0], ny = g[1], nz = g[2];
    const float rx = cx - nx, ry = cy - ny, rz = cz - nz;
    const float dist = sqrtf(rx * rx + ry * ry + rz * rz);
    float* st = s + tid * 10;
    st[0] = dist; st[1] = rx; st[2] = ry; st[3] = rz;
    st[4] = cx;   st[5] = cy; st[6] = cz;
    st[7] = nx;   st[8] = ny; st[9] = nz;
    __syncthreads();
    float4* o4 = (float4*)(out + (size_t)blockIdx.x * 2560);
    const float4* s4 = (const float4*)s;
    o4[tid]       = s4[tid];
    o4[tid + 256] = s4[tid + 256];
    if (tid < 128) o4[tid + 512] = s4[tid + 512];
}

__global__ __launch_bounds__(256) void pool_kernel_naive(
    const float* __restrict__ feat, const int* __restrict__ pidx,
    float* __restrict__ out)
{
    const int i  = blockIdx.x * 256 + threadIdx.x;
    const int np = i & (NPOOL - 1);
    const int bd = i >> 14;
    const int b  = bd >> 5;
    const int4* ip = (const int4*)(pidx + (size_t)(b * NPOOL + np) * KNBR);
    const float* f = feat + (size_t)bd * NPTS;
    float m = -INFINITY;
    #pragma unroll
    for (int q = 0; q < 4; ++q) {
        const int4 v = ip[q];
        m = fmaxf(m, f[v.x]); m = fmaxf(m, f[v.y]);
        m = fmaxf(m, f[v.z]); m = fmaxf(m, f[v.w]);
    }
    out[i] = m;
}

__global__ __launch_bounds__(256) void interp_kernel_naive(
    const float* __restrict__ feat, const int* __restrict__ iidx,
    float* __restrict__ out)
{
    const int i  = blockIdx.x * 256 + threadIdx.x;
    const int u  = i & (NPTS - 1);
    const int bd = i >> 16;
    const int b  = bd >> 5;
    out[i] = feat[(size_t)bd * NPOOL + iidx[b * NPTS + u]];
}

extern "C" void kernel_launch(void* const* d_in, const int* in_sizes, int n_in,
                              void* d_out, int out_size, void* d_ws, size_t ws_size,
                              hipStream_t stream) {
    const float* xyz         = (const float*)d_in[0];
    const int*   neigh_idx   = (const int*)d_in[1];
    const float* feat_pool   = (const float*)d_in[2];
    const int*   pool_idx    = (const int*)d_in[3];
    const float* feat_interp = (const float*)d_in[4];
    const int*   interp_idx  = (const int*)d_in[5];

    float* out    = (float*)d_out;
    float* rel    = out;                                        // [4,65536,16,10]
    float* pooled = rel + (size_t)BATCH * NPTS * KNBR * 10;     // [4,32,16384]
    float* interp = pooled + (size_t)BATCH * DF * NPOOL;        // [4,32,65536]

    const size_t need = (FTP_ELEMS + FTI_ELEMS + XYZ4_ELEMS) * sizeof(float);
    if (ws_size >= need) {
        float* ftp  = (float*)d_ws;
        float* fti  = ftp + FTP_ELEMS;
        float* xyz4 = fti + FTI_ELEMS;
        prep_kernel<<<T1_BLKS + T2_BLKS + T3_BLKS, 256, 0, stream>>>(
            feat_pool, feat_interp, xyz, ftp, fti, xyz4);
        fused_main<<<MAIN_BLKS, 256, 0, stream>>>(
            xyz4, neigh_idx, ftp, pool_idx, fti, interp_idx, rel, pooled, interp);
    } else {
        relpos_kernel<<<(BATCH * NPTS * KNBR) / 256, 256, 0, stream>>>(xyz, neigh_idx, rel);
        pool_kernel_naive<<<(BATCH * DF * NPOOL) / 256, 256, 0, stream>>>(feat_pool, pool_idx, pooled);
        interp_kernel_naive<<<(BATCH * DF * NPTS) / 256, 256, 0, stream>>>(feat_interp, interp_idx, interp);
    }
}

// Round 9
// 308.838 us; speedup vs baseline: 1.0771x; 1.0108x over previous
//
#include <hip/hip_runtime.h>
#include <math.h>

#define BATCH 4
#define NPTS  65536
#define KNBR  16
#define DF    32
#define NPOOL 16384   // NPTS/4

typedef float f32x4 __attribute__((ext_vector_type(4)));

// ws layout: ftp [B][NPTS][32] | fti [B][NPOOL][32]
#define FTP_ELEMS   ((size_t)BATCH * NPTS * DF)
#define FTI_ELEMS   ((size_t)BATCH * NPOOL * DF)

#define T1_BLKS (BATCH * (NPTS / 32))    // 8192 transpose blocks (feat_pool)
#define T2_BLKS (BATCH * (NPOOL / 32))   // 2048 transpose blocks (feat_interp)
#define R_BLKS  ((BATCH * NPTS * KNBR) / 256)   // 16384 relpos blocks
// kernel A: groups of 13 = 5 transpose + 8 relpos; 2048 groups
#define A_GROUPS 2048
#define A_BLKS  (A_GROUPS * 13)          // 26624 = 10240 T + 16384 R

// kernel B: groups of 5 = 1 pool + 4 interp; 1024 groups
#define P_BLKS 1024                      // B * NPOOL/64
#define I_BLKS 4096                      // B * NPTS/64
#define B_BLKS (P_BLKS + I_BLKS)         // 5120

// ============ Kernel A: transposes (read-bound) ∥ relpos (write-bound) ====
__global__ __launch_bounds__(256) void streamA_kernel(
    const float* __restrict__ xyz, const int* __restrict__ nidx,
    const float* __restrict__ feat_pool, const float* __restrict__ feat_interp,
    float* __restrict__ ftp, float* __restrict__ fti, float* __restrict__ rel)
{
    __shared__ float smem[2560];
    const int g = blockIdx.x / 13;
    const int m = blockIdx.x % 13;
    const int t = threadIdx.x;

    if (m < 5) {
        // -------- transpose [b][d][nn] tile -> [b][nn][d] ----------------
        float (*tile)[33] = (float(*)[33])smem;
        int tb = g * 5 + m;
        const float* in; float* outp; int nn;
        if (tb < T1_BLKS) { in = feat_pool;   outp = ftp; nn = NPTS; }
        else              { in = feat_interp; outp = fti; nn = NPOOL; tb -= T1_BLKS; }
        const int tpb = nn >> 5;
        const int b  = tb / tpb;
        const int n0 = (tb % tpb) << 5;
        const int nl = t & 31;
        const int dl = t >> 5;
        #pragma unroll
        for (int it = 0; it < 4; ++it) {
            const int d = dl + it * 8;
            tile[d][nl] = __builtin_nontemporal_load(&in[(size_t)(b * DF + d) * nn + n0 + nl]);
        }
        __syncthreads();
        #pragma unroll
        for (int it = 0; it < 4; ++it) {
            const int n = dl + it * 8;
            outp[((size_t)b * nn + n0 + n) * DF + nl] = tile[nl][n];  // re-read later: cacheable
        }
    } else {
        // -------- relpos: 256 (b,n,k) entries, direct xyz reads ----------
        const int rblk = g * 8 + (m - 5);
        const int e = rblk * 256 + t;                 // b*2^20 + n*16 + k
        const int b = e >> 20;
        const int n = (e >> 4) & (NPTS - 1);
        const int j = __builtin_nontemporal_load(&nidx[e]);   // one-pass stream
        const float* cp = xyz + (size_t)(b * NPTS + n) * 3;
        const float* qp = xyz + (size_t)(b * NPTS + j) * 3;   // xyz is L2-resident (3MB)
        const float cx = cp[0], cy = cp[1], cz = cp[2];
        const float qx = qp[0], qy = qp[1], qz = qp[2];
        const float rx = cx - qx, ry = cy - qy, rz = cz - qz;
        const float dist = sqrtf(rx * rx + ry * ry + rz * rz);
        float* st = smem + t * 10;
        st[0] = dist; st[1] = rx; st[2] = ry; st[3] = rz;
        st[4] = cx;   st[5] = cy; st[6] = cz;
        st[7] = qx;   st[8] = qy; st[9] = qz;
        __syncthreads();
        f32x4* o4 = (f32x4*)(rel + (size_t)rblk * 2560);
        const f32x4* s4 = (const f32x4*)smem;
        __builtin_nontemporal_store(s4[t],       &o4[t]);
        __builtin_nontemporal_store(s4[t + 256], &o4[t + 256]);
        if (t < 128) __builtin_nontemporal_store(s4[t + 512], &o4[t + 512]);
    }
}

// ============ Kernel B: pool + interp gathers, float4 outputs =============
__global__ __launch_bounds__(256) void gatherB_kernel(
    const float* __restrict__ ftp, const int* __restrict__ pidx,
    const float* __restrict__ fti, const int* __restrict__ iidx,
    float* __restrict__ pooled, float* __restrict__ interp)
{
    __shared__ char smem[12544];
    const int g = blockIdx.x / 5;
    const int m = blockIdx.x % 5;
    const int t = threadIdx.x;

    if (m == 0) {
        // -------- pool: (b, 64 np rows) ----------------------------------
        int*   s_idx = (int*)smem;                   // 1024 ints
        float* s_out = (float*)(smem + 4096);        // 64*33 floats
        const int bpb = NPOOL / 64;                  // 256
        const int b   = g / bpb;
        const int np0 = (g % bpb) * 64;
        ((int4*)s_idx)[t] = ((const int4*)(pidx + (size_t)(b * NPOOL + np0) * KNBR))[t];
        __syncthreads();
        const float4* fb4 = (const float4*)(ftp + (size_t)b * NPTS * DF);
        const int l8 = t & 7;                        // 8 lanes x float4 = 32 d
        #pragma unroll
        for (int it = 0; it < 2; ++it) {
            const int u = (t >> 3) + it * 32;
            float4 acc = make_float4(-INFINITY, -INFINITY, -INFINITY, -INFINITY);
            #pragma unroll
            for (int k = 0; k < KNBR; ++k) {
                const int idx = s_idx[u * KNBR + k];
                const float4 v = fb4[(size_t)idx * 8 + l8];
                acc.x = fmaxf(acc.x, v.x); acc.y = fmaxf(acc.y, v.y);
                acc.z = fmaxf(acc.z, v.z); acc.w = fmaxf(acc.w, v.w);
            }
            float* so = s_out + u * 33 + l8 * 4;
            so[0] = acc.x; so[1] = acc.y; so[2] = acc.z; so[3] = acc.w;
        }
        __syncthreads();
        #pragma unroll
        for (int it = 0; it < 2; ++it) {             // 512 float4s / 256 thr
            const int flat = it * 256 + t;
            const int dd = flat >> 4;
            const int u  = (flat & 15) * 4;
            f32x4 v = { s_out[(u + 0) * 33 + dd], s_out[(u + 1) * 33 + dd],
                        s_out[(u + 2) * 33 + dd], s_out[(u + 3) * 33 + dd] };
            __builtin_nontemporal_store(v,
                (f32x4*)&pooled[(size_t)(b * DF + dd) * NPOOL + np0 + u]);
        }
    } else {
        // -------- interp: (b, 64 u rows) ---------------------------------
        int*   s_idx = (int*)smem;                   // 64 ints
        float* s_out = (float*)(smem + 256);         // 64*33 floats
        const int i   = g * 4 + (m - 1);
        const int bpb = NPTS / 64;                   // 1024
        const int b   = i / bpb;
        const int u0  = (i % bpb) * 64;
        if (t < 64) s_idx[t] = iidx[b * NPTS + u0 + t];
        __syncthreads();
        const float4* fb4 = (const float4*)(fti + (size_t)b * NPOOL * DF);
        const int l8 = t & 7;
        #pragma unroll
        for (int it = 0; it < 2; ++it) {
            const int u = (t >> 3) + it * 32;
            const int idx = s_idx[u];
            const float4 v = fb4[(size_t)idx * 8 + l8];
            float* so = s_out + u * 33 + l8 * 4;
            so[0] = v.x; so[1] = v.y; so[2] = v.z; so[3] = v.w;
        }
        __syncthreads();
        #pragma unroll
        for (int it = 0; it < 2; ++it) {
            const int flat = it * 256 + t;
            const int dd = flat >> 4;
            const int u  = (flat & 15) * 4;
            f32x4 v = { s_out[(u + 0) * 33 + dd], s_out[(u + 1) * 33 + dd],
                        s_out[(u + 2) * 33 + dd], s_out[(u + 3) * 33 + dd] };
            __builtin_nontemporal_store(v,
                (f32x4*)&interp[(size_t)(b * DF + dd) * NPTS + u0 + u]);
        }
    }
}

// ================== Fallback path (ws too small) =========================
__global__ __launch_bounds__(256) void relpos_kernel(
    const float* __restrict__ xyz, const int* __restrict__ nidx,
    float* __restrict__ out)
{
    __shared__ float s[2560];
    const int tid = threadIdx.x;
    const int e = blockIdx.x * 256 + tid;
    const int b = e >> 20;
    const int n = (e >> 4) & (NPTS - 1);
    const int j = nidx[e];
    const float* c = xyz + (size_t)(b * NPTS + n) * 3;
    const float* g = xyz + (size_t)(b * NPTS + j) * 3;
    const float cx = c[0], cy = c[1], cz = c[2];
    const float nx = g[0], ny = g[1], nz = g[2];
    const float rx = cx - nx, ry = cy - ny, rz = cz - nz;
    const float dist = sqrtf(rx * rx + ry * ry + rz * rz);
    float* st = s + tid * 10;
    st[0] = dist; st[1] = rx; st[2] = ry; st[3] = rz;
    st[4] = cx;   st[5] = cy; st[6] = cz;
    st[7] = nx;   st[8] = ny; st[9] = nz;
    __syncthreads();
    float4* o4 = (float4*)(out + (size_t)blockIdx.x * 2560);
    const float4* s4 = (const float4*)s;
    o4[tid]       = s4[tid];
    o4[tid + 256] = s4[tid + 256];
    if (tid < 128) o4[tid + 512] = s4[tid + 512];
}

__global__ __launch_bounds__(256) void pool_kernel_naive(
    const float* __restrict__ feat, const int* __restrict__ pidx,
    float* __restrict__ out)
{
    const int i  = blockIdx.x * 256 + threadIdx.x;
    const int np = i & (NPOOL - 1);
    const int bd = i >> 14;
    const int b  = bd >> 5;
    const int4* ip = (const int4*)(pidx + (size_t)(b * NPOOL + np) * KNBR);
    const float* f = feat + (size_t)bd * NPTS;
    float m = -INFINITY;
    #pragma unroll
    for (int q = 0; q < 4; ++q) {
        const int4 v = ip[q];
        m = fmaxf(m, f[v.x]); m = fmaxf(m, f[v.y]);
        m = fmaxf(m, f[v.z]); m = fmaxf(m, f[v.w]);
    }
    out[i] = m;
}

__global__ __launch_bounds__(256) void interp_kernel_naive(
    const float* __restrict__ feat, const int* __restrict__ iidx,
    float* __restrict__ out)
{
    const int i  = blockIdx.x * 256 + threadIdx.x;
    const int u  = i & (NPTS - 1);
    const int bd = i >> 16;
    const int b  = bd >> 5;
    out[i] = feat[(size_t)bd * NPOOL + iidx[b * NPTS + u]];
}

extern "C" void kernel_launch(void* const* d_in, const int* in_sizes, int n_in,
                              void* d_out, int out_size, void* d_ws, size_t ws_size,
                              hipStream_t stream) {
    const float* xyz         = (const float*)d_in[0];
    const int*   neigh_idx   = (const int*)d_in[1];
    const float* feat_pool   = (const float*)d_in[2];
    const int*   pool_idx    = (const int*)d_in[3];
    const float* feat_interp = (const float*)d_in[4];
    const int*   interp_idx  = (const int*)d_in[5];

    float* out    = (float*)d_out;
    float* rel    = out;                                        // [4,65536,16,10]
    float* pooled = rel + (size_t)BATCH * NPTS * KNBR * 10;     // [4,32,16384]
    float* interp = pooled + (size_t)BATCH * DF * NPOOL;        // [4,32,65536]

    const size_t need = (FTP_ELEMS + FTI_ELEMS) * sizeof(float);
    if (ws_size >= need) {
        float* ftp = (float*)d_ws;                              // [4,65536,32]
        float* fti = ftp + FTP_ELEMS;                           // [4,16384,32]
        streamA_kernel<<<A_BLKS, 256, 0, stream>>>(
            xyz, neigh_idx, feat_pool, feat_interp, ftp, fti, rel);
        gatherB_kernel<<<B_BLKS, 256, 0, stream>>>(
            ftp, pool_idx, fti, interp_idx, pooled, interp);
    } else {
        relpos_kernel<<<R_BLKS, 256, 0, stream>>>(xyz, neigh_idx, rel);
        pool_kernel_naive<<<(BATCH * DF * NPOOL) / 256, 256, 0, stream>>>(feat_pool, pool_idx, pooled);
        interp_kernel_naive<<<(BATCH * DF * NPTS) / 256, 256, 0, stream>>>(feat_interp, interp_idx, interp);
    }
}